// Round 3
// baseline (6111.722 us; speedup 1.0000x reference)
//
#include <hip/hip_runtime.h>

#define NUM_USERS 100000
#define NUM_ITEMS 50000
#define N_NODES   150000
#define EMB_DIM   64
#define NNZ       4800000
#define N_LAYERS  3

#define TILE_ROWS 256
#define TILE_SHIFT 8
#define NTILES    ((N_NODES + TILE_ROWS - 1) / TILE_ROWS)   // 586
#define COL_BITS  18
#define COL_MASK  ((1 << COL_BITS) - 1)

static constexpr size_t TOTAL = (size_t)N_NODES * EMB_DIM;   // 9,600,000 floats

// ---------------- init: cur = acc = concat(user_emb, item_emb) ----------------
__global__ void lgcn_init(const float4* __restrict__ user_emb,
                          const float4* __restrict__ item_emb,
                          float4* __restrict__ cur,
                          float4* __restrict__ acc) {
    size_t i = (size_t)blockIdx.x * blockDim.x + threadIdx.x;
    const size_t n4 = TOTAL / 4;
    if (i >= n4) return;
    const size_t ub4 = (size_t)NUM_USERS * EMB_DIM / 4;
    float4 v = (i < ub4) ? user_emb[i] : item_emb[i - ub4];
    cur[i] = v;
    acc[i] = v;
}

// ---------------- tile histogram (LDS-staged) ----------------
__global__ void tile_hist(const int* __restrict__ rows, int* __restrict__ tileCnt) {
    __shared__ int h[NTILES];
    for (int i = threadIdx.x; i < NTILES; i += blockDim.x) h[i] = 0;
    __syncthreads();
    for (size_t e = (size_t)blockIdx.x * blockDim.x + threadIdx.x; e < NNZ;
         e += (size_t)gridDim.x * blockDim.x)
        atomicAdd(&h[rows[e] >> TILE_SHIFT], 1);
    __syncthreads();
    for (int i = threadIdx.x; i < NTILES; i += blockDim.x) {
        int c = h[i];
        if (c) atomicAdd(&tileCnt[i], c);
    }
}

// ---------------- scan of 586 tile counts (single block) ----------------
__global__ void tile_scan(const int* __restrict__ tileCnt,
                          int* __restrict__ tile_ptr,
                          int* __restrict__ tile_cursor) {
    __shared__ int s[1024];
    int t = threadIdx.x;
    int v = (t < NTILES) ? tileCnt[t] : 0;
    s[t] = v;
    __syncthreads();
    for (int off = 1; off < 1024; off <<= 1) {
        int add = (t >= off) ? s[t - off] : 0;
        __syncthreads();
        s[t] += add;
        __syncthreads();
    }
    if (t < NTILES) {
        int ex = s[t] - v;
        tile_ptr[t] = ex;
        tile_cursor[t] = ex;
    }
    if (t == 0) tile_ptr[NTILES] = NNZ;
}

// ---------------- LDS-staged bucketing: coalesced writes of tile-grouped edges ----------------
#define BKT_BLK 1024
#define EPB     8192    // edges per block (8 per thread)

__global__ __launch_bounds__(BKT_BLK) void
edge_bucket(const int* __restrict__ rows, const int* __restrict__ cols,
            const float* __restrict__ vals, int* __restrict__ tile_cursor,
            int2* __restrict__ edges) {
    __shared__ int2 stage[EPB];     // 64 KB
    __shared__ int  dstIdx[EPB];    // 32 KB
    __shared__ int  hcur[NTILES];   // count -> inclusive scan -> local cursor
    __shared__ int  lbase[NTILES];
    __shared__ int  gbase[NTILES];

    int tid = threadIdx.x;
    size_t blockStart = (size_t)blockIdx.x * EPB;

    int r[8]; int c[8]; float v[8];
    for (int i = tid; i < NTILES; i += BKT_BLK) hcur[i] = 0;
    __syncthreads();

    #pragma unroll
    for (int k = 0; k < 8; k++) {
        size_t e = blockStart + (size_t)k * BKT_BLK + tid;
        if (e < NNZ) {
            r[k] = rows[e]; c[k] = cols[e]; v[k] = vals[e];
            atomicAdd(&hcur[r[k] >> TILE_SHIFT], 1);
        } else r[k] = -1;
    }
    __syncthreads();

    int cnt = (tid < NTILES) ? hcur[tid] : 0;
    // Hillis-Steele inclusive scan of hcur[0..NTILES)
    for (int off = 1; off < 1024; off <<= 1) {
        int add = (tid >= off && tid < NTILES) ? hcur[tid - off] : 0;
        __syncthreads();
        if (tid < NTILES) hcur[tid] += add;
        __syncthreads();
    }
    if (tid < NTILES) {
        int ex = hcur[tid] - cnt;
        lbase[tid] = ex;
        gbase[tid] = cnt ? atomicAdd(&tile_cursor[tid], cnt) : 0;
    }
    __syncthreads();
    if (tid < NTILES) hcur[tid] = lbase[tid];   // reuse as local run cursor
    __syncthreads();

    #pragma unroll
    for (int k = 0; k < 8; k++) {
        if (r[k] >= 0) {
            int t = r[k] >> TILE_SHIFT;
            int slot = atomicAdd(&hcur[t], 1);
            stage[slot] = make_int2(((r[k] & (TILE_ROWS - 1)) << COL_BITS) | c[k],
                                    __float_as_int(v[k]));
            dstIdx[slot] = gbase[t] + (slot - lbase[t]);
        }
    }
    __syncthreads();

    int total = (int)min((size_t)EPB, (size_t)NNZ - blockStart);
    for (int i = tid; i < total; i += BKT_BLK)
        edges[dstIdx[i]] = stage[i];   // coalesced within per-tile runs
}

// ---------------- tiled SpMM with LDS accumulator ----------------
#define SPMM_BLK 512

__global__ __launch_bounds__(SPMM_BLK) void
lgcn_spmm_tile(const int* __restrict__ tile_ptr, const int2* __restrict__ edges,
               const float* __restrict__ x, float* __restrict__ y,
               float* __restrict__ acc, float scale) {
    __shared__ float lacc[TILE_ROWS * EMB_DIM];   // 64 KB
    float4* lacc4 = (float4*)lacc;
    int tid = threadIdx.x;
    int tile = blockIdx.x;

    for (int i = tid; i < TILE_ROWS * EMB_DIM / 4; i += SPMM_BLK)
        lacc4[i] = make_float4(0.f, 0.f, 0.f, 0.f);
    __syncthreads();

    int s  = tile_ptr[tile];
    int e1 = tile_ptr[tile + 1];
    int w = tid >> 6, lane = tid & 63;
    const int NW = SPMM_BLK / 64;          // 8 waves
    for (int bb = s + w * 8; bb < e1; bb += NW * 8) {
        int n = e1 - bb;
        if (n >= 8) {
            int2 m0 = edges[bb+0], m1 = edges[bb+1], m2 = edges[bb+2], m3 = edges[bb+3];
            int2 m4 = edges[bb+4], m5 = edges[bb+5], m6 = edges[bb+6], m7 = edges[bb+7];
            float x0 = x[(size_t)(m0.x & COL_MASK) * EMB_DIM + lane];
            float x1 = x[(size_t)(m1.x & COL_MASK) * EMB_DIM + lane];
            float x2 = x[(size_t)(m2.x & COL_MASK) * EMB_DIM + lane];
            float x3 = x[(size_t)(m3.x & COL_MASK) * EMB_DIM + lane];
            float x4 = x[(size_t)(m4.x & COL_MASK) * EMB_DIM + lane];
            float x5 = x[(size_t)(m5.x & COL_MASK) * EMB_DIM + lane];
            float x6 = x[(size_t)(m6.x & COL_MASK) * EMB_DIM + lane];
            float x7 = x[(size_t)(m7.x & COL_MASK) * EMB_DIM + lane];
            atomicAdd(&lacc[((unsigned)m0.x >> COL_BITS) * EMB_DIM + lane], __int_as_float(m0.y) * x0);
            atomicAdd(&lacc[((unsigned)m1.x >> COL_BITS) * EMB_DIM + lane], __int_as_float(m1.y) * x1);
            atomicAdd(&lacc[((unsigned)m2.x >> COL_BITS) * EMB_DIM + lane], __int_as_float(m2.y) * x2);
            atomicAdd(&lacc[((unsigned)m3.x >> COL_BITS) * EMB_DIM + lane], __int_as_float(m3.y) * x3);
            atomicAdd(&lacc[((unsigned)m4.x >> COL_BITS) * EMB_DIM + lane], __int_as_float(m4.y) * x4);
            atomicAdd(&lacc[((unsigned)m5.x >> COL_BITS) * EMB_DIM + lane], __int_as_float(m5.y) * x5);
            atomicAdd(&lacc[((unsigned)m6.x >> COL_BITS) * EMB_DIM + lane], __int_as_float(m6.y) * x6);
            atomicAdd(&lacc[((unsigned)m7.x >> COL_BITS) * EMB_DIM + lane], __int_as_float(m7.y) * x7);
        } else {
            for (int j = 0; j < n; ++j) {
                int2 m = edges[bb + j];
                float xv = x[(size_t)(m.x & COL_MASK) * EMB_DIM + lane];
                atomicAdd(&lacc[((unsigned)m.x >> COL_BITS) * EMB_DIM + lane],
                          __int_as_float(m.y) * xv);
            }
        }
    }
    __syncthreads();

    // epilogue: y = lacc; acc = (acc + lacc) * scale  (coalesced float4)
    size_t tbase4 = (size_t)tile * (TILE_ROWS * EMB_DIM / 4);
    for (int i = tid; i < TILE_ROWS * EMB_DIM / 4; i += SPMM_BLK) {
        int rowG = tile * TILE_ROWS + (i >> 4);
        if (rowG < N_NODES) {
            float4 a = lacc4[i];
            size_t o = tbase4 + i;
            ((float4*)y)[o] = a;
            float4 ov = ((float4*)acc)[o];
            ov.x = (ov.x + a.x) * scale;
            ov.y = (ov.y + a.y) * scale;
            ov.z = (ov.z + a.z) * scale;
            ov.w = (ov.w + a.w) * scale;
            ((float4*)acc)[o] = ov;
        }
    }
}

// ---------------- fallback (round-1 atomic path), used if ws too small ----------------
__global__ void lgcn_spmm_scatter(const int* __restrict__ rows,
                                  const int* __restrict__ cols,
                                  const float* __restrict__ vals,
                                  const float* __restrict__ x,
                                  float* __restrict__ y) {
    size_t t = (size_t)blockIdx.x * blockDim.x + threadIdx.x;
    if (t >= (size_t)NNZ * EMB_DIM) return;
    int e = (int)(t >> 6);
    int d = (int)(t & 63);
    atomicAdd(&y[(size_t)rows[e] * EMB_DIM + d], vals[e] * x[(size_t)cols[e] * EMB_DIM + d]);
}

__global__ void lgcn_accum(float4* __restrict__ acc, const float4* __restrict__ nxt, float scale) {
    size_t i = (size_t)blockIdx.x * blockDim.x + threadIdx.x;
    const size_t n4 = TOTAL / 4;
    if (i >= n4) return;
    float4 a = acc[i]; float4 b = nxt[i];
    a.x = (a.x + b.x) * scale; a.y = (a.y + b.y) * scale;
    a.z = (a.z + b.z) * scale; a.w = (a.w + b.w) * scale;
    acc[i] = a;
}

extern "C" void kernel_launch(void* const* d_in, const int* in_sizes, int n_in,
                              void* d_out, int out_size, void* d_ws, size_t ws_size,
                              hipStream_t stream) {
    const float* user_emb = (const float*)d_in[0];
    const float* item_emb = (const float*)d_in[1];
    const int*   rows     = (const int*)d_in[2];
    const int*   cols     = (const int*)d_in[3];
    const float* vals     = (const float*)d_in[4];
    float* out = (float*)d_out;

    const int BLK = 256;
    const size_t n4 = TOTAL / 4;
    dim3 g_init((n4 + BLK - 1) / BLK);

    // workspace layout
    char* p = (char*)d_ws;
    float* cur = (float*)p;        p += TOTAL * sizeof(float);        // 38.4 MB
    float* nxt = (float*)p;        p += TOTAL * sizeof(float);        // 38.4 MB
    int2*  edges = (int2*)p;       p += (size_t)NNZ * sizeof(int2);   // 38.4 MB
    int*   tileCnt = (int*)p;      p += (size_t)NTILES * sizeof(int);
    int*   tile_ptr = (int*)p;     p += (size_t)(NTILES + 1) * sizeof(int);
    int*   tile_cursor = (int*)p;  p += (size_t)NTILES * sizeof(int);
    size_t needed = (size_t)(p - (char*)d_ws);

    if (ws_size < needed) {
        lgcn_init<<<g_init, BLK, 0, stream>>>((const float4*)user_emb, (const float4*)item_emb,
                                              (float4*)cur, (float4*)out);
        const size_t st = (size_t)NNZ * EMB_DIM;
        dim3 g_scat((st + BLK - 1) / BLK);
        for (int l = 0; l < N_LAYERS; ++l) {
            hipMemsetAsync(nxt, 0, TOTAL * sizeof(float), stream);
            lgcn_spmm_scatter<<<g_scat, BLK, 0, stream>>>(rows, cols, vals, cur, nxt);
            float scale = (l == N_LAYERS - 1) ? (1.0f / (N_LAYERS + 1)) : 1.0f;
            lgcn_accum<<<g_init, BLK, 0, stream>>>((float4*)out, (const float4*)nxt, scale);
            float* t = cur; cur = nxt; nxt = t;
        }
        return;
    }

    // ---- tile bucketing (once per call) ----
    hipMemsetAsync(tileCnt, 0, (size_t)NTILES * sizeof(int), stream);
    tile_hist<<<1024, 256, 0, stream>>>(rows, tileCnt);
    tile_scan<<<1, 1024, 0, stream>>>(tileCnt, tile_ptr, tile_cursor);
    int nBuckBlocks = (NNZ + EPB - 1) / EPB;   // 586
    edge_bucket<<<nBuckBlocks, BKT_BLK, 0, stream>>>(rows, cols, vals, tile_cursor, edges);

    // ---- init ----
    lgcn_init<<<g_init, BLK, 0, stream>>>((const float4*)user_emb, (const float4*)item_emb,
                                          (float4*)cur, (float4*)out);

    // ---- 3 layers of tiled SpMM with fused accumulation ----
    for (int l = 0; l < N_LAYERS; ++l) {
        float scale = (l == N_LAYERS - 1) ? (1.0f / (N_LAYERS + 1)) : 1.0f;
        lgcn_spmm_tile<<<NTILES, SPMM_BLK, 0, stream>>>(tile_ptr, edges, cur, nxt, out, scale);
        float* t = cur; cur = nxt; nxt = t;
    }
}

// Round 4
// 677.502 us; speedup vs baseline: 9.0210x; 9.0210x over previous
//
#include <hip/hip_runtime.h>

#define NUM_USERS 100000
#define NUM_ITEMS 50000
#define N_NODES   150000
#define EMB_DIM   64
#define NNZ       4800000
#define N_LAYERS  3

#define TILE_ROWS 256
#define TILE_SHIFT 8
#define NTILES    ((N_NODES + TILE_ROWS - 1) / TILE_ROWS)   // 586
#define COL_BITS  18
#define COL_MASK  ((1 << COL_BITS) - 1)

static constexpr size_t TOTAL = (size_t)N_NODES * EMB_DIM;   // 9,600,000 floats

// ---------------- init: cur = acc = concat(user_emb, item_emb) ----------------
__global__ void lgcn_init(const float4* __restrict__ user_emb,
                          const float4* __restrict__ item_emb,
                          float4* __restrict__ cur,
                          float4* __restrict__ acc) {
    size_t i = (size_t)blockIdx.x * blockDim.x + threadIdx.x;
    const size_t n4 = TOTAL / 4;
    if (i >= n4) return;
    const size_t ub4 = (size_t)NUM_USERS * EMB_DIM / 4;
    float4 v = (i < ub4) ? user_emb[i] : item_emb[i - ub4];
    cur[i] = v;
    acc[i] = v;
}

// ---------------- tile histogram ----------------
__global__ void tile_hist(const int* __restrict__ rows, int* __restrict__ tileCnt) {
    __shared__ int h[NTILES];
    for (int i = threadIdx.x; i < NTILES; i += blockDim.x) h[i] = 0;
    __syncthreads();
    for (size_t e = (size_t)blockIdx.x * blockDim.x + threadIdx.x; e < NNZ;
         e += (size_t)gridDim.x * blockDim.x)
        atomicAdd(&h[rows[e] >> TILE_SHIFT], 1);
    __syncthreads();
    for (int i = threadIdx.x; i < NTILES; i += blockDim.x) {
        int c = h[i];
        if (c) atomicAdd(&tileCnt[i], c);
    }
}

// ---------------- scan of 586 tile counts (single block) ----------------
__global__ void tile_scan(const int* __restrict__ tileCnt,
                          int* __restrict__ tile_ptr,
                          int* __restrict__ tile_cursor,
                          int* __restrict__ row_ptr) {
    __shared__ int s[1024];
    int t = threadIdx.x;
    int v = (t < NTILES) ? tileCnt[t] : 0;
    s[t] = v;
    __syncthreads();
    for (int off = 1; off < 1024; off <<= 1) {
        int add = (t >= off) ? s[t - off] : 0;
        __syncthreads();
        s[t] += add;
        __syncthreads();
    }
    if (t < NTILES) {
        int ex = s[t] - v;
        tile_ptr[t] = ex;
        tile_cursor[t] = ex;
    }
    if (t == 0) {
        tile_ptr[NTILES] = NNZ;
        row_ptr[N_NODES] = NNZ;
    }
}

// ---------------- pass 1: LDS-staged bucketing by 256-row tile ----------------
#define BKT_BLK 1024
#define EPB     8192    // edges per block (8 per thread)

__global__ __launch_bounds__(BKT_BLK) void
edge_bucket(const int* __restrict__ rows, const int* __restrict__ cols,
            const float* __restrict__ vals, int* __restrict__ tile_cursor,
            int2* __restrict__ ebuf1) {
    __shared__ int2 stage[EPB];     // 64 KB
    __shared__ int  dstIdx[EPB];    // 32 KB
    __shared__ int  hcur[NTILES];
    __shared__ int  lbase[NTILES];
    __shared__ int  gbase[NTILES];

    int tid = threadIdx.x;
    size_t blockStart = (size_t)blockIdx.x * EPB;

    int r[8]; int c[8]; float v[8];
    for (int i = tid; i < NTILES; i += BKT_BLK) hcur[i] = 0;
    __syncthreads();

    #pragma unroll
    for (int k = 0; k < 8; k++) {
        size_t e = blockStart + (size_t)k * BKT_BLK + tid;
        if (e < NNZ) {
            r[k] = rows[e]; c[k] = cols[e]; v[k] = vals[e];
            atomicAdd(&hcur[r[k] >> TILE_SHIFT], 1);
        } else r[k] = -1;
    }
    __syncthreads();

    int cnt = (tid < NTILES) ? hcur[tid] : 0;
    for (int off = 1; off < 1024; off <<= 1) {
        int add = (tid >= off && tid < NTILES) ? hcur[tid - off] : 0;
        __syncthreads();
        if (tid < NTILES) hcur[tid] += add;
        __syncthreads();
    }
    if (tid < NTILES) {
        int ex = hcur[tid] - cnt;
        lbase[tid] = ex;
        gbase[tid] = cnt ? atomicAdd(&tile_cursor[tid], cnt) : 0;
    }
    __syncthreads();
    if (tid < NTILES) hcur[tid] = lbase[tid];
    __syncthreads();

    #pragma unroll
    for (int k = 0; k < 8; k++) {
        if (r[k] >= 0) {
            int t = r[k] >> TILE_SHIFT;
            int slot = atomicAdd(&hcur[t], 1);
            stage[slot] = make_int2(((r[k] & (TILE_ROWS - 1)) << COL_BITS) | c[k],
                                    __float_as_int(v[k]));
            dstIdx[slot] = gbase[t] + (slot - lbase[t]);
        }
    }
    __syncthreads();

    int total = (int)min((size_t)EPB, (size_t)NNZ - blockStart);
    for (int i = tid; i < total; i += BKT_BLK)
        ebuf1[dstIdx[i]] = stage[i];   // coalesced within per-tile runs
}

// ---------------- pass 2: within-tile sort by row; emits row_ptr + (col,val) ----------------
#define RS_BLK 512

__global__ __launch_bounds__(RS_BLK) void
row_sort(const int2* __restrict__ ebuf1, const int* __restrict__ tile_ptr,
         int* __restrict__ row_ptr, int2* __restrict__ ebuf2) {
    __shared__ int hist[TILE_ROWS];
    __shared__ int cur256[TILE_ROWS];
    int tid = threadIdx.x;
    int tile = blockIdx.x;
    int s  = tile_ptr[tile];
    int e1 = tile_ptr[tile + 1];

    if (tid < TILE_ROWS) hist[tid] = 0;
    __syncthreads();

    for (int i = s + tid; i < e1; i += RS_BLK)
        atomicAdd(&hist[(unsigned)ebuf1[i].x >> COL_BITS], 1);
    __syncthreads();

    // Hillis-Steele inclusive scan over 256 entries
    int v = (tid < TILE_ROWS) ? hist[tid] : 0;
    for (int off = 1; off < TILE_ROWS; off <<= 1) {
        int add = (tid >= off && tid < TILE_ROWS) ? hist[tid - off] : 0;
        __syncthreads();
        if (tid < TILE_ROWS) hist[tid] += add;
        __syncthreads();
    }
    if (tid < TILE_ROWS) {
        int excl = hist[tid] - v;
        int rowG = tile * TILE_ROWS + tid;
        if (rowG < N_NODES) row_ptr[rowG] = s + excl;
        cur256[tid] = s + excl;
    }
    __syncthreads();

    for (int i = s + tid; i < e1; i += RS_BLK) {
        int2 m = ebuf1[i];
        int r = (unsigned)m.x >> COL_BITS;
        int pos = atomicAdd(&cur256[r], 1);
        ebuf2[pos] = make_int2(m.x & COL_MASK, m.y);   // scatter within 64KB window (L2)
    }
}

// ---------------- gather SpMM: one wave per row, lane = dim, 8-deep ILP ----------------
__global__ void lgcn_spmm_csr(const int* __restrict__ row_ptr,
                              const int2* __restrict__ edges,
                              const float* __restrict__ x,
                              float* __restrict__ y,
                              float* __restrict__ acc,
                              float scale) {
    int wid = blockIdx.x * (blockDim.x >> 6) + (threadIdx.x >> 6);
    if (wid >= N_NODES) return;
    int lane = threadIdx.x & 63;
    int e  = row_ptr[wid];
    int e1 = row_ptr[wid + 1];
    float a = 0.0f;
    for (; e + 8 <= e1; e += 8) {
        int2 m0 = edges[e+0], m1 = edges[e+1], m2 = edges[e+2], m3 = edges[e+3];
        int2 m4 = edges[e+4], m5 = edges[e+5], m6 = edges[e+6], m7 = edges[e+7];
        float x0 = x[(size_t)m0.x * EMB_DIM + lane];
        float x1 = x[(size_t)m1.x * EMB_DIM + lane];
        float x2 = x[(size_t)m2.x * EMB_DIM + lane];
        float x3 = x[(size_t)m3.x * EMB_DIM + lane];
        float x4 = x[(size_t)m4.x * EMB_DIM + lane];
        float x5 = x[(size_t)m5.x * EMB_DIM + lane];
        float x6 = x[(size_t)m6.x * EMB_DIM + lane];
        float x7 = x[(size_t)m7.x * EMB_DIM + lane];
        a = fmaf(__int_as_float(m0.y), x0, a);
        a = fmaf(__int_as_float(m1.y), x1, a);
        a = fmaf(__int_as_float(m2.y), x2, a);
        a = fmaf(__int_as_float(m3.y), x3, a);
        a = fmaf(__int_as_float(m4.y), x4, a);
        a = fmaf(__int_as_float(m5.y), x5, a);
        a = fmaf(__int_as_float(m6.y), x6, a);
        a = fmaf(__int_as_float(m7.y), x7, a);
    }
    for (; e < e1; ++e) {
        int2 m = edges[e];
        a = fmaf(__int_as_float(m.y), x[(size_t)m.x * EMB_DIM + lane], a);
    }
    size_t o = (size_t)wid * EMB_DIM + lane;
    y[o] = a;
    acc[o] = (acc[o] + a) * scale;
}

// ---------------- fallback (round-1 atomic path), used if ws too small ----------------
__global__ void lgcn_spmm_scatter(const int* __restrict__ rows,
                                  const int* __restrict__ cols,
                                  const float* __restrict__ vals,
                                  const float* __restrict__ x,
                                  float* __restrict__ y) {
    size_t t = (size_t)blockIdx.x * blockDim.x + threadIdx.x;
    if (t >= (size_t)NNZ * EMB_DIM) return;
    int e = (int)(t >> 6);
    int d = (int)(t & 63);
    atomicAdd(&y[(size_t)rows[e] * EMB_DIM + d], vals[e] * x[(size_t)cols[e] * EMB_DIM + d]);
}

__global__ void lgcn_accum(float4* __restrict__ acc, const float4* __restrict__ nxt, float scale) {
    size_t i = (size_t)blockIdx.x * blockDim.x + threadIdx.x;
    const size_t n4 = TOTAL / 4;
    if (i >= n4) return;
    float4 a = acc[i]; float4 b = nxt[i];
    a.x = (a.x + b.x) * scale; a.y = (a.y + b.y) * scale;
    a.z = (a.z + b.z) * scale; a.w = (a.w + b.w) * scale;
    acc[i] = a;
}

extern "C" void kernel_launch(void* const* d_in, const int* in_sizes, int n_in,
                              void* d_out, int out_size, void* d_ws, size_t ws_size,
                              hipStream_t stream) {
    const float* user_emb = (const float*)d_in[0];
    const float* item_emb = (const float*)d_in[1];
    const int*   rows     = (const int*)d_in[2];
    const int*   cols     = (const int*)d_in[3];
    const float* vals     = (const float*)d_in[4];
    float* out = (float*)d_out;

    const int BLK = 256;
    const size_t n4 = TOTAL / 4;
    dim3 g_init((n4 + BLK - 1) / BLK);

    // workspace layout — cur ALIASES ebuf1 (ebuf1 dead after row_sort)
    char* p = (char*)d_ws;
    int2*  ebuf2 = (int2*)p;       p += (size_t)NNZ * sizeof(int2);   // 38.4 MB (final edges)
    float* cur = (float*)p;                                            // aliases ebuf1
    int2*  ebuf1 = (int2*)p;       p += (size_t)NNZ * sizeof(int2);   // 38.4 MB
    float* nxt = (float*)p;        p += TOTAL * sizeof(float);        // 38.4 MB
    int*   tileCnt = (int*)p;      p += (size_t)NTILES * sizeof(int);
    int*   tile_ptr = (int*)p;     p += (size_t)(NTILES + 1) * sizeof(int);
    int*   tile_cursor = (int*)p;  p += (size_t)NTILES * sizeof(int);
    int*   row_ptr = (int*)p;      p += (size_t)(N_NODES + 1) * sizeof(int);
    size_t needed = (size_t)(p - (char*)d_ws);

    if (ws_size < needed) {
        float* fcur = (float*)d_ws;
        float* fnxt = fcur + TOTAL;
        lgcn_init<<<g_init, BLK, 0, stream>>>((const float4*)user_emb, (const float4*)item_emb,
                                              (float4*)fcur, (float4*)out);
        const size_t st = (size_t)NNZ * EMB_DIM;
        dim3 g_scat((st + BLK - 1) / BLK);
        for (int l = 0; l < N_LAYERS; ++l) {
            hipMemsetAsync(fnxt, 0, TOTAL * sizeof(float), stream);
            lgcn_spmm_scatter<<<g_scat, BLK, 0, stream>>>(rows, cols, vals, fcur, fnxt);
            float scale = (l == N_LAYERS - 1) ? (1.0f / (N_LAYERS + 1)) : 1.0f;
            lgcn_accum<<<g_init, BLK, 0, stream>>>((float4*)out, (const float4*)fnxt, scale);
            float* t = fcur; fcur = fnxt; fnxt = t;
        }
        return;
    }

    // ---- two-pass row sort (once per call) ----
    hipMemsetAsync(tileCnt, 0, (size_t)NTILES * sizeof(int), stream);
    tile_hist<<<1024, 256, 0, stream>>>(rows, tileCnt);
    tile_scan<<<1, 1024, 0, stream>>>(tileCnt, tile_ptr, tile_cursor, row_ptr);
    int nBuckBlocks = (NNZ + EPB - 1) / EPB;   // 586
    edge_bucket<<<nBuckBlocks, BKT_BLK, 0, stream>>>(rows, cols, vals, tile_cursor, ebuf1);
    row_sort<<<NTILES, RS_BLK, 0, stream>>>(ebuf1, tile_ptr, row_ptr, ebuf2);

    // ---- init (cur overwrites ebuf1, which is now dead) ----
    lgcn_init<<<g_init, BLK, 0, stream>>>((const float4*)user_emb, (const float4*)item_emb,
                                          (float4*)cur, (float4*)out);

    // ---- 3 layers of CSR gather SpMM with fused accumulation ----
    const int WAVES_PER_BLK = BLK / 64;
    dim3 g_spmm((N_NODES + WAVES_PER_BLK - 1) / WAVES_PER_BLK);
    float* xa = cur; float* xb = nxt;
    for (int l = 0; l < N_LAYERS; ++l) {
        float scale = (l == N_LAYERS - 1) ? (1.0f / (N_LAYERS + 1)) : 1.0f;
        lgcn_spmm_csr<<<g_spmm, BLK, 0, stream>>>(row_ptr, ebuf2, xa, xb, out, scale);
        float* t = xa; xa = xb; xb = t;
    }
}

// Round 5
// 563.885 us; speedup vs baseline: 10.8386x; 1.2015x over previous
//
#include <hip/hip_runtime.h>
#include <hip/hip_fp16.h>

#define NUM_USERS 100000
#define NUM_ITEMS 50000
#define N_NODES   150000
#define EMB_DIM   64
#define NNZ       4800000
#define N_LAYERS  3

#define TILE_ROWS 256
#define TILE_SHIFT 8
#define NTILES    ((N_NODES + TILE_ROWS - 1) / TILE_ROWS)   // 586
#define COL_BITS  18
#define COL_MASK  ((1 << COL_BITS) - 1)

static constexpr size_t TOTAL = (size_t)N_NODES * EMB_DIM;   // 9,600,000 floats

// ---------------- init: cur16 = fp16(concat), acc = concat (f32) ----------------
__global__ void lgcn_init_h(const float4* __restrict__ user_emb,
                            const float4* __restrict__ item_emb,
                            uint2* __restrict__ cur16,
                            float4* __restrict__ acc) {
    size_t i = (size_t)blockIdx.x * blockDim.x + threadIdx.x;
    const size_t n4 = TOTAL / 4;
    if (i >= n4) return;
    const size_t ub4 = (size_t)NUM_USERS * EMB_DIM / 4;
    float4 v = (i < ub4) ? user_emb[i] : item_emb[i - ub4];
    acc[i] = v;
    __half2 h0 = __floats2half2_rn(v.x, v.y);
    __half2 h1 = __floats2half2_rn(v.z, v.w);
    uint2 u;
    u.x = *reinterpret_cast<unsigned int*>(&h0);
    u.y = *reinterpret_cast<unsigned int*>(&h1);
    cur16[i] = u;
}

// ---------------- tile histogram ----------------
__global__ void tile_hist(const int* __restrict__ rows, int* __restrict__ tileCnt) {
    __shared__ int h[NTILES];
    for (int i = threadIdx.x; i < NTILES; i += blockDim.x) h[i] = 0;
    __syncthreads();
    for (size_t e = (size_t)blockIdx.x * blockDim.x + threadIdx.x; e < NNZ;
         e += (size_t)gridDim.x * blockDim.x)
        atomicAdd(&h[rows[e] >> TILE_SHIFT], 1);
    __syncthreads();
    for (int i = threadIdx.x; i < NTILES; i += blockDim.x) {
        int c = h[i];
        if (c) atomicAdd(&tileCnt[i], c);
    }
}

// ---------------- scan of 586 tile counts (single block) ----------------
__global__ void tile_scan(const int* __restrict__ tileCnt,
                          int* __restrict__ tile_ptr,
                          int* __restrict__ tile_cursor,
                          int* __restrict__ row_ptr) {
    __shared__ int s[1024];
    int t = threadIdx.x;
    int v = (t < NTILES) ? tileCnt[t] : 0;
    s[t] = v;
    __syncthreads();
    for (int off = 1; off < 1024; off <<= 1) {
        int add = (t >= off) ? s[t - off] : 0;
        __syncthreads();
        s[t] += add;
        __syncthreads();
    }
    if (t < NTILES) {
        int ex = s[t] - v;
        tile_ptr[t] = ex;
        tile_cursor[t] = ex;
    }
    if (t == 0) {
        tile_ptr[NTILES] = NNZ;
        row_ptr[N_NODES] = NNZ;
    }
}

// ---------------- pass 1: LDS-staged bucketing by 256-row tile ----------------
#define BKT_BLK 1024
#define EPB     8192    // edges per block (8 per thread)

__global__ __launch_bounds__(BKT_BLK) void
edge_bucket(const int* __restrict__ rows, const int* __restrict__ cols,
            const float* __restrict__ vals, int* __restrict__ tile_cursor,
            int2* __restrict__ ebuf1) {
    __shared__ int2 stage[EPB];     // 64 KB
    __shared__ int  dstIdx[EPB];    // 32 KB
    __shared__ int  hcur[NTILES];
    __shared__ int  lbase[NTILES];
    __shared__ int  gbase[NTILES];

    int tid = threadIdx.x;
    size_t blockStart = (size_t)blockIdx.x * EPB;

    int r[8]; int c[8]; float v[8];
    for (int i = tid; i < NTILES; i += BKT_BLK) hcur[i] = 0;
    __syncthreads();

    #pragma unroll
    for (int k = 0; k < 8; k++) {
        size_t e = blockStart + (size_t)k * BKT_BLK + tid;
        if (e < NNZ) {
            r[k] = rows[e]; c[k] = cols[e]; v[k] = vals[e];
            atomicAdd(&hcur[r[k] >> TILE_SHIFT], 1);
        } else r[k] = -1;
    }
    __syncthreads();

    int cnt = (tid < NTILES) ? hcur[tid] : 0;
    for (int off = 1; off < 1024; off <<= 1) {
        int add = (tid >= off && tid < NTILES) ? hcur[tid - off] : 0;
        __syncthreads();
        if (tid < NTILES) hcur[tid] += add;
        __syncthreads();
    }
    if (tid < NTILES) {
        int ex = hcur[tid] - cnt;
        lbase[tid] = ex;
        gbase[tid] = cnt ? atomicAdd(&tile_cursor[tid], cnt) : 0;
    }
    __syncthreads();
    if (tid < NTILES) hcur[tid] = lbase[tid];
    __syncthreads();

    #pragma unroll
    for (int k = 0; k < 8; k++) {
        if (r[k] >= 0) {
            int t = r[k] >> TILE_SHIFT;
            int slot = atomicAdd(&hcur[t], 1);
            stage[slot] = make_int2(((r[k] & (TILE_ROWS - 1)) << COL_BITS) | c[k],
                                    __float_as_int(v[k]));
            dstIdx[slot] = gbase[t] + (slot - lbase[t]);
        }
    }
    __syncthreads();

    int total = (int)min((size_t)EPB, (size_t)NNZ - blockStart);
    for (int i = tid; i < total; i += BKT_BLK)
        ebuf1[dstIdx[i]] = stage[i];   // coalesced within per-tile runs
}

// ---------------- pass 2: within-tile sort by row; emits row_ptr + (col,val) ----------------
#define RS_BLK 512

__global__ __launch_bounds__(RS_BLK) void
row_sort(const int2* __restrict__ ebuf1, const int* __restrict__ tile_ptr,
         int* __restrict__ row_ptr, int2* __restrict__ ebuf2) {
    __shared__ int hist[TILE_ROWS];
    __shared__ int cur256[TILE_ROWS];
    int tid = threadIdx.x;
    int tile = blockIdx.x;
    int s  = tile_ptr[tile];
    int e1 = tile_ptr[tile + 1];

    if (tid < TILE_ROWS) hist[tid] = 0;
    __syncthreads();

    for (int i = s + tid; i < e1; i += RS_BLK)
        atomicAdd(&hist[(unsigned)ebuf1[i].x >> COL_BITS], 1);
    __syncthreads();

    int v = (tid < TILE_ROWS) ? hist[tid] : 0;
    for (int off = 1; off < TILE_ROWS; off <<= 1) {
        int add = (tid >= off && tid < TILE_ROWS) ? hist[tid - off] : 0;
        __syncthreads();
        if (tid < TILE_ROWS) hist[tid] += add;
        __syncthreads();
    }
    if (tid < TILE_ROWS) {
        int excl = hist[tid] - v;
        int rowG = tile * TILE_ROWS + tid;
        if (rowG < N_NODES) row_ptr[rowG] = s + excl;
        cur256[tid] = s + excl;
    }
    __syncthreads();

    for (int i = s + tid; i < e1; i += RS_BLK) {
        int2 m = ebuf1[i];
        int r = (unsigned)m.x >> COL_BITS;
        int pos = atomicAdd(&cur256[r], 1);
        ebuf2[pos] = make_int2(m.x & COL_MASK, m.y);   // scatter within 64KB window (L2)
    }
}

// ---------------- gather SpMM (fp16 operand, f32 accumulate) ----------------
__global__ void lgcn_spmm_csr_h(const int* __restrict__ row_ptr,
                                const int2* __restrict__ edges,
                                const __half* __restrict__ x16,
                                __half* __restrict__ y16,
                                float* __restrict__ acc,
                                float scale, int writeY) {
    int wid = blockIdx.x * (blockDim.x >> 6) + (threadIdx.x >> 6);
    if (wid >= N_NODES) return;
    int lane = threadIdx.x & 63;
    int e  = row_ptr[wid];
    int e1 = row_ptr[wid + 1];
    float a = 0.0f;
    for (; e + 8 <= e1; e += 8) {
        int2 m0 = edges[e+0], m1 = edges[e+1], m2 = edges[e+2], m3 = edges[e+3];
        int2 m4 = edges[e+4], m5 = edges[e+5], m6 = edges[e+6], m7 = edges[e+7];
        float x0 = __half2float(x16[(size_t)m0.x * EMB_DIM + lane]);
        float x1 = __half2float(x16[(size_t)m1.x * EMB_DIM + lane]);
        float x2 = __half2float(x16[(size_t)m2.x * EMB_DIM + lane]);
        float x3 = __half2float(x16[(size_t)m3.x * EMB_DIM + lane]);
        float x4 = __half2float(x16[(size_t)m4.x * EMB_DIM + lane]);
        float x5 = __half2float(x16[(size_t)m5.x * EMB_DIM + lane]);
        float x6 = __half2float(x16[(size_t)m6.x * EMB_DIM + lane]);
        float x7 = __half2float(x16[(size_t)m7.x * EMB_DIM + lane]);
        a = fmaf(__int_as_float(m0.y), x0, a);
        a = fmaf(__int_as_float(m1.y), x1, a);
        a = fmaf(__int_as_float(m2.y), x2, a);
        a = fmaf(__int_as_float(m3.y), x3, a);
        a = fmaf(__int_as_float(m4.y), x4, a);
        a = fmaf(__int_as_float(m5.y), x5, a);
        a = fmaf(__int_as_float(m6.y), x6, a);
        a = fmaf(__int_as_float(m7.y), x7, a);
    }
    for (; e < e1; ++e) {
        int2 m = edges[e];
        a = fmaf(__int_as_float(m.y), __half2float(x16[(size_t)m.x * EMB_DIM + lane]), a);
    }
    size_t o = (size_t)wid * EMB_DIM + lane;
    acc[o] = (acc[o] + a) * scale;
    if (writeY) y16[o] = __float2half_rn(a);
}

// ---------------- fallback (round-1 atomic path), used if ws too small ----------------
__global__ void lgcn_init_f(const float4* __restrict__ user_emb,
                            const float4* __restrict__ item_emb,
                            float4* __restrict__ cur,
                            float4* __restrict__ acc) {
    size_t i = (size_t)blockIdx.x * blockDim.x + threadIdx.x;
    const size_t n4 = TOTAL / 4;
    if (i >= n4) return;
    const size_t ub4 = (size_t)NUM_USERS * EMB_DIM / 4;
    float4 v = (i < ub4) ? user_emb[i] : item_emb[i - ub4];
    cur[i] = v;
    acc[i] = v;
}

__global__ void lgcn_spmm_scatter(const int* __restrict__ rows,
                                  const int* __restrict__ cols,
                                  const float* __restrict__ vals,
                                  const float* __restrict__ x,
                                  float* __restrict__ y) {
    size_t t = (size_t)blockIdx.x * blockDim.x + threadIdx.x;
    if (t >= (size_t)NNZ * EMB_DIM) return;
    int e = (int)(t >> 6);
    int d = (int)(t & 63);
    atomicAdd(&y[(size_t)rows[e] * EMB_DIM + d], vals[e] * x[(size_t)cols[e] * EMB_DIM + d]);
}

__global__ void lgcn_accum(float4* __restrict__ acc, const float4* __restrict__ nxt, float scale) {
    size_t i = (size_t)blockIdx.x * blockDim.x + threadIdx.x;
    const size_t n4 = TOTAL / 4;
    if (i >= n4) return;
    float4 a = acc[i]; float4 b = nxt[i];
    a.x = (a.x + b.x) * scale; a.y = (a.y + b.y) * scale;
    a.z = (a.z + b.z) * scale; a.w = (a.w + b.w) * scale;
    acc[i] = a;
}

extern "C" void kernel_launch(void* const* d_in, const int* in_sizes, int n_in,
                              void* d_out, int out_size, void* d_ws, size_t ws_size,
                              hipStream_t stream) {
    const float* user_emb = (const float*)d_in[0];
    const float* item_emb = (const float*)d_in[1];
    const int*   rows     = (const int*)d_in[2];
    const int*   cols     = (const int*)d_in[3];
    const float* vals     = (const float*)d_in[4];
    float* out = (float*)d_out;

    const int BLK = 256;
    const size_t n4 = TOTAL / 4;
    dim3 g_init((n4 + BLK - 1) / BLK);

    // workspace layout — cur16 ALIASES ebuf1 (ebuf1 dead after row_sort)
    char* p = (char*)d_ws;
    int2*   ebuf2 = (int2*)p;      p += (size_t)NNZ * sizeof(int2);   // 38.4 MB (final edges)
    __half* cur16 = (__half*)p;                                        // 19.2 MB, aliases ebuf1
    int2*   ebuf1 = (int2*)p;      p += (size_t)NNZ * sizeof(int2);   // 38.4 MB
    __half* nxt16 = (__half*)p;    p += TOTAL * sizeof(__half);       // 19.2 MB
    int*    tileCnt = (int*)p;     p += (size_t)NTILES * sizeof(int);
    int*    tile_ptr = (int*)p;    p += (size_t)(NTILES + 1) * sizeof(int);
    int*    tile_cursor = (int*)p; p += (size_t)NTILES * sizeof(int);
    int*    row_ptr = (int*)p;     p += (size_t)(N_NODES + 1) * sizeof(int);
    size_t needed = (size_t)(p - (char*)d_ws);

    if (ws_size < needed) {
        float* fcur = (float*)d_ws;
        float* fnxt = fcur + TOTAL;
        lgcn_init_f<<<g_init, BLK, 0, stream>>>((const float4*)user_emb, (const float4*)item_emb,
                                                (float4*)fcur, (float4*)out);
        const size_t st = (size_t)NNZ * EMB_DIM;
        dim3 g_scat((st + BLK - 1) / BLK);
        for (int l = 0; l < N_LAYERS; ++l) {
            hipMemsetAsync(fnxt, 0, TOTAL * sizeof(float), stream);
            lgcn_spmm_scatter<<<g_scat, BLK, 0, stream>>>(rows, cols, vals, fcur, fnxt);
            float scale = (l == N_LAYERS - 1) ? (1.0f / (N_LAYERS + 1)) : 1.0f;
            lgcn_accum<<<g_init, BLK, 0, stream>>>((float4*)out, (const float4*)fnxt, scale);
            float* t = fcur; fcur = fnxt; fnxt = t;
        }
        return;
    }

    // ---- two-pass row sort (once per call) ----
    hipMemsetAsync(tileCnt, 0, (size_t)NTILES * sizeof(int), stream);
    tile_hist<<<1024, 256, 0, stream>>>(rows, tileCnt);
    tile_scan<<<1, 1024, 0, stream>>>(tileCnt, tile_ptr, tile_cursor, row_ptr);
    int nBuckBlocks = (NNZ + EPB - 1) / EPB;   // 586
    edge_bucket<<<nBuckBlocks, BKT_BLK, 0, stream>>>(rows, cols, vals, tile_cursor, ebuf1);
    row_sort<<<NTILES, RS_BLK, 0, stream>>>(ebuf1, tile_ptr, row_ptr, ebuf2);

    // ---- init (cur16 overwrites ebuf1, which is now dead) ----
    lgcn_init_h<<<g_init, BLK, 0, stream>>>((const float4*)user_emb, (const float4*)item_emb,
                                            (uint2*)cur16, (float4*)out);

    // ---- 3 layers of CSR gather SpMM (fp16 operand, f32 acc) ----
    const int WAVES_PER_BLK = BLK / 64;
    dim3 g_spmm((N_NODES + WAVES_PER_BLK - 1) / WAVES_PER_BLK);
    __half* xa = cur16; __half* xb = nxt16;
    for (int l = 0; l < N_LAYERS; ++l) {
        float scale = (l == N_LAYERS - 1) ? (1.0f / (N_LAYERS + 1)) : 1.0f;
        int writeY = (l < N_LAYERS - 1) ? 1 : 0;
        lgcn_spmm_csr_h<<<g_spmm, BLK, 0, stream>>>(row_ptr, ebuf2, xa, xb, out, scale, writeY);
        __half* t = xa; xa = xb; xb = t;
    }
}

// Round 6
// 451.331 us; speedup vs baseline: 13.5416x; 1.2494x over previous
//
#include <hip/hip_runtime.h>
#include <hip/hip_fp16.h>

#define NUM_USERS 100000
#define NUM_ITEMS 50000
#define N_NODES   150000
#define EMB_DIM   64
#define NNZ       4800000
#define N_LAYERS  3

#define TILE_ROWS 256
#define TILE_SHIFT 8
#define NTILES    ((N_NODES + TILE_ROWS - 1) / TILE_ROWS)   // 586
#define COL_BITS  18
#define COL_MASK  ((1 << COL_BITS) - 1)

static constexpr size_t TOTAL = (size_t)N_NODES * EMB_DIM;   // 9,600,000 floats

// ---------------- init: cur16 = fp16(concat), acc = concat (f32) ----------------
__global__ void lgcn_init_h(const float4* __restrict__ user_emb,
                            const float4* __restrict__ item_emb,
                            uint2* __restrict__ cur16,
                            float4* __restrict__ acc) {
    size_t i = (size_t)blockIdx.x * blockDim.x + threadIdx.x;
    const size_t n4 = TOTAL / 4;
    if (i >= n4) return;
    const size_t ub4 = (size_t)NUM_USERS * EMB_DIM / 4;
    float4 v = (i < ub4) ? user_emb[i] : item_emb[i - ub4];
    acc[i] = v;
    __half2 h0 = __floats2half2_rn(v.x, v.y);
    __half2 h1 = __floats2half2_rn(v.z, v.w);
    uint2 u;
    u.x = *reinterpret_cast<unsigned int*>(&h0);
    u.y = *reinterpret_cast<unsigned int*>(&h1);
    cur16[i] = u;
}

// ---------------- tile histogram ----------------
__global__ void tile_hist(const int* __restrict__ rows, int* __restrict__ tileCnt) {
    __shared__ int h[NTILES];
    for (int i = threadIdx.x; i < NTILES; i += blockDim.x) h[i] = 0;
    __syncthreads();
    for (size_t e = (size_t)blockIdx.x * blockDim.x + threadIdx.x; e < NNZ;
         e += (size_t)gridDim.x * blockDim.x)
        atomicAdd(&h[rows[e] >> TILE_SHIFT], 1);
    __syncthreads();
    for (int i = threadIdx.x; i < NTILES; i += blockDim.x) {
        int c = h[i];
        if (c) atomicAdd(&tileCnt[i], c);
    }
}

// ---------------- scan of 586 tile counts (single block) ----------------
__global__ void tile_scan(const int* __restrict__ tileCnt,
                          int* __restrict__ tile_ptr,
                          int* __restrict__ tile_cursor,
                          int* __restrict__ row_ptr) {
    __shared__ int s[1024];
    int t = threadIdx.x;
    int v = (t < NTILES) ? tileCnt[t] : 0;
    s[t] = v;
    __syncthreads();
    for (int off = 1; off < 1024; off <<= 1) {
        int add = (t >= off) ? s[t - off] : 0;
        __syncthreads();
        s[t] += add;
        __syncthreads();
    }
    if (t < NTILES) {
        int ex = s[t] - v;
        tile_ptr[t] = ex;
        tile_cursor[t] = ex;
    }
    if (t == 0) {
        tile_ptr[NTILES] = NNZ;
        row_ptr[N_NODES] = NNZ;
    }
}

// ---------------- pass 1: LDS-staged bucketing by 256-row tile ----------------
#define BKT_BLK 1024
#define EPB     8192    // edges per block (8 per thread)

__global__ __launch_bounds__(BKT_BLK) void
edge_bucket(const int* __restrict__ rows, const int* __restrict__ cols,
            const float* __restrict__ vals, int* __restrict__ tile_cursor,
            int2* __restrict__ ebuf1) {
    __shared__ int2 stage[EPB];     // 64 KB
    __shared__ int  dstIdx[EPB];    // 32 KB
    __shared__ int  hcur[NTILES];
    __shared__ int  lbase[NTILES];
    __shared__ int  gbase[NTILES];

    int tid = threadIdx.x;
    size_t blockStart = (size_t)blockIdx.x * EPB;

    int r[8]; int c[8]; float v[8];
    for (int i = tid; i < NTILES; i += BKT_BLK) hcur[i] = 0;
    __syncthreads();

    #pragma unroll
    for (int k = 0; k < 8; k++) {
        size_t e = blockStart + (size_t)k * BKT_BLK + tid;
        if (e < NNZ) {
            r[k] = rows[e]; c[k] = cols[e]; v[k] = vals[e];
            atomicAdd(&hcur[r[k] >> TILE_SHIFT], 1);
        } else r[k] = -1;
    }
    __syncthreads();

    int cnt = (tid < NTILES) ? hcur[tid] : 0;
    for (int off = 1; off < 1024; off <<= 1) {
        int add = (tid >= off && tid < NTILES) ? hcur[tid - off] : 0;
        __syncthreads();
        if (tid < NTILES) hcur[tid] += add;
        __syncthreads();
    }
    if (tid < NTILES) {
        int ex = hcur[tid] - cnt;
        lbase[tid] = ex;
        gbase[tid] = cnt ? atomicAdd(&tile_cursor[tid], cnt) : 0;
    }
    __syncthreads();
    if (tid < NTILES) hcur[tid] = lbase[tid];
    __syncthreads();

    #pragma unroll
    for (int k = 0; k < 8; k++) {
        if (r[k] >= 0) {
            int t = r[k] >> TILE_SHIFT;
            int slot = atomicAdd(&hcur[t], 1);
            stage[slot] = make_int2(((r[k] & (TILE_ROWS - 1)) << COL_BITS) | c[k],
                                    __float_as_int(v[k]));
            dstIdx[slot] = gbase[t] + (slot - lbase[t]);
        }
    }
    __syncthreads();

    int total = (int)min((size_t)EPB, (size_t)NNZ - blockStart);
    for (int i = tid; i < total; i += BKT_BLK)
        ebuf1[dstIdx[i]] = stage[i];   // coalesced within per-tile runs
}

// ---------------- pass 2: within-tile sort by row; emits row_ptr + (col,val) ----------------
#define RS_BLK 512

__global__ __launch_bounds__(RS_BLK) void
row_sort(const int2* __restrict__ ebuf1, const int* __restrict__ tile_ptr,
         int* __restrict__ row_ptr, int2* __restrict__ ebuf2) {
    __shared__ int hist[TILE_ROWS];
    __shared__ int cur256[TILE_ROWS];
    int tid = threadIdx.x;
    int tile = blockIdx.x;
    int s  = tile_ptr[tile];
    int e1 = tile_ptr[tile + 1];

    if (tid < TILE_ROWS) hist[tid] = 0;
    __syncthreads();

    for (int i = s + tid; i < e1; i += RS_BLK)
        atomicAdd(&hist[(unsigned)ebuf1[i].x >> COL_BITS], 1);
    __syncthreads();

    int v = (tid < TILE_ROWS) ? hist[tid] : 0;
    for (int off = 1; off < TILE_ROWS; off <<= 1) {
        int add = (tid >= off && tid < TILE_ROWS) ? hist[tid - off] : 0;
        __syncthreads();
        if (tid < TILE_ROWS) hist[tid] += add;
        __syncthreads();
    }
    if (tid < TILE_ROWS) {
        int excl = hist[tid] - v;
        int rowG = tile * TILE_ROWS + tid;
        if (rowG < N_NODES) row_ptr[rowG] = s + excl;
        cur256[tid] = s + excl;
    }
    __syncthreads();

    for (int i = s + tid; i < e1; i += RS_BLK) {
        int2 m = ebuf1[i];
        int r = (unsigned)m.x >> COL_BITS;
        int pos = atomicAdd(&cur256[r], 1);
        ebuf2[pos] = make_int2(m.x & COL_MASK, m.y);   // scatter within 64KB window (L2)
    }
}

// ---------------- gather SpMM: 4 edge-substreams x 16 lanes, uint2 (4xfp16) loads ----------------
__device__ __forceinline__ void fma4(uint2 xv, float v,
                                     float& a0, float& a1, float& a2, float& a3) {
    __half2 h0 = *reinterpret_cast<__half2*>(&xv.x);
    __half2 h1 = *reinterpret_cast<__half2*>(&xv.y);
    float2 f0 = __half22float2(h0);
    float2 f1 = __half22float2(h1);
    a0 = fmaf(v, f0.x, a0);
    a1 = fmaf(v, f0.y, a1);
    a2 = fmaf(v, f1.x, a2);
    a3 = fmaf(v, f1.y, a3);
}

__global__ void lgcn_spmm_csr_h4(const int* __restrict__ row_ptr,
                                 const int2* __restrict__ edges,
                                 const uint2* __restrict__ x16v,
                                 uint2* __restrict__ y16v,
                                 float4* __restrict__ acc4,
                                 float scale, int writeY) {
    int wid = blockIdx.x * (blockDim.x >> 6) + (threadIdx.x >> 6);
    if (wid >= N_NODES) return;
    int lane = threadIdx.x & 63;
    int g = lane >> 4;       // edge substream 0..3
    int t = lane & 15;       // dim group: dims 4t..4t+3
    int e  = row_ptr[wid];
    int e1 = row_ptr[wid + 1];
    float a0 = 0.f, a1 = 0.f, a2 = 0.f, a3 = 0.f;

    for (; e + 8 <= e1; e += 8) {
        int2 mA = edges[e + g];
        int2 mB = edges[e + 4 + g];
        uint2 xA = x16v[(size_t)mA.x * 16 + t];
        uint2 xB = x16v[(size_t)mB.x * 16 + t];
        fma4(xA, __int_as_float(mA.y), a0, a1, a2, a3);
        fma4(xB, __int_as_float(mB.y), a0, a1, a2, a3);
    }
    if (e + 4 <= e1) {
        int2 m = edges[e + g];
        uint2 xv = x16v[(size_t)m.x * 16 + t];
        fma4(xv, __int_as_float(m.y), a0, a1, a2, a3);
        e += 4;
    }
    int rem = e1 - e;        // 0..3
    if (g < rem) {
        int2 m = edges[e + g];
        uint2 xv = x16v[(size_t)m.x * 16 + t];
        fma4(xv, __int_as_float(m.y), a0, a1, a2, a3);
    }

    // fold the 4 substreams
    a0 += __shfl_xor(a0, 16); a1 += __shfl_xor(a1, 16);
    a2 += __shfl_xor(a2, 16); a3 += __shfl_xor(a3, 16);
    a0 += __shfl_xor(a0, 32); a1 += __shfl_xor(a1, 32);
    a2 += __shfl_xor(a2, 32); a3 += __shfl_xor(a3, 32);

    if (lane < 16) {
        size_t o = (size_t)wid * 16 + t;
        float4 av = acc4[o];
        av.x = (av.x + a0) * scale;
        av.y = (av.y + a1) * scale;
        av.z = (av.z + a2) * scale;
        av.w = (av.w + a3) * scale;
        acc4[o] = av;
        if (writeY) {
            __half2 h0 = __floats2half2_rn(a0, a1);
            __half2 h1 = __floats2half2_rn(a2, a3);
            uint2 u;
            u.x = *reinterpret_cast<unsigned int*>(&h0);
            u.y = *reinterpret_cast<unsigned int*>(&h1);
            y16v[o] = u;
        }
    }
}

// ---------------- fallback (round-1 atomic path), used if ws too small ----------------
__global__ void lgcn_init_f(const float4* __restrict__ user_emb,
                            const float4* __restrict__ item_emb,
                            float4* __restrict__ cur,
                            float4* __restrict__ acc) {
    size_t i = (size_t)blockIdx.x * blockDim.x + threadIdx.x;
    const size_t n4 = TOTAL / 4;
    if (i >= n4) return;
    const size_t ub4 = (size_t)NUM_USERS * EMB_DIM / 4;
    float4 v = (i < ub4) ? user_emb[i] : item_emb[i - ub4];
    cur[i] = v;
    acc[i] = v;
}

__global__ void lgcn_spmm_scatter(const int* __restrict__ rows,
                                  const int* __restrict__ cols,
                                  const float* __restrict__ vals,
                                  const float* __restrict__ x,
                                  float* __restrict__ y) {
    size_t t = (size_t)blockIdx.x * blockDim.x + threadIdx.x;
    if (t >= (size_t)NNZ * EMB_DIM) return;
    int e = (int)(t >> 6);
    int d = (int)(t & 63);
    atomicAdd(&y[(size_t)rows[e] * EMB_DIM + d], vals[e] * x[(size_t)cols[e] * EMB_DIM + d]);
}

__global__ void lgcn_accum(float4* __restrict__ acc, const float4* __restrict__ nxt, float scale) {
    size_t i = (size_t)blockIdx.x * blockDim.x + threadIdx.x;
    const size_t n4 = TOTAL / 4;
    if (i >= n4) return;
    float4 a = acc[i]; float4 b = nxt[i];
    a.x = (a.x + b.x) * scale; a.y = (a.y + b.y) * scale;
    a.z = (a.z + b.z) * scale; a.w = (a.w + b.w) * scale;
    acc[i] = a;
}

extern "C" void kernel_launch(void* const* d_in, const int* in_sizes, int n_in,
                              void* d_out, int out_size, void* d_ws, size_t ws_size,
                              hipStream_t stream) {
    const float* user_emb = (const float*)d_in[0];
    const float* item_emb = (const float*)d_in[1];
    const int*   rows     = (const int*)d_in[2];
    const int*   cols     = (const int*)d_in[3];
    const float* vals     = (const float*)d_in[4];
    float* out = (float*)d_out;

    const int BLK = 256;
    const size_t n4 = TOTAL / 4;
    dim3 g_init((n4 + BLK - 1) / BLK);

    // workspace layout — cur16 ALIASES ebuf1 (ebuf1 dead after row_sort)
    char* p = (char*)d_ws;
    int2*   ebuf2 = (int2*)p;      p += (size_t)NNZ * sizeof(int2);   // 38.4 MB (final edges)
    __half* cur16 = (__half*)p;                                        // 19.2 MB, aliases ebuf1
    int2*   ebuf1 = (int2*)p;      p += (size_t)NNZ * sizeof(int2);   // 38.4 MB
    __half* nxt16 = (__half*)p;    p += TOTAL * sizeof(__half);       // 19.2 MB
    int*    tileCnt = (int*)p;     p += (size_t)NTILES * sizeof(int);
    int*    tile_ptr = (int*)p;    p += (size_t)(NTILES + 1) * sizeof(int);
    int*    tile_cursor = (int*)p; p += (size_t)NTILES * sizeof(int);
    int*    row_ptr = (int*)p;     p += (size_t)(N_NODES + 1) * sizeof(int);
    size_t needed = (size_t)(p - (char*)d_ws);

    if (ws_size < needed) {
        float* fcur = (float*)d_ws;
        float* fnxt = fcur + TOTAL;
        lgcn_init_f<<<g_init, BLK, 0, stream>>>((const float4*)user_emb, (const float4*)item_emb,
                                                (float4*)fcur, (float4*)out);
        const size_t st = (size_t)NNZ * EMB_DIM;
        dim3 g_scat((st + BLK - 1) / BLK);
        for (int l = 0; l < N_LAYERS; ++l) {
            hipMemsetAsync(fnxt, 0, TOTAL * sizeof(float), stream);
            lgcn_spmm_scatter<<<g_scat, BLK, 0, stream>>>(rows, cols, vals, fcur, fnxt);
            float scale = (l == N_LAYERS - 1) ? (1.0f / (N_LAYERS + 1)) : 1.0f;
            lgcn_accum<<<g_init, BLK, 0, stream>>>((float4*)out, (const float4*)fnxt, scale);
            float* t = fcur; fcur = fnxt; fnxt = t;
        }
        return;
    }

    // ---- two-pass row sort (once per call) ----
    hipMemsetAsync(tileCnt, 0, (size_t)NTILES * sizeof(int), stream);
    tile_hist<<<1024, 256, 0, stream>>>(rows, tileCnt);
    tile_scan<<<1, 1024, 0, stream>>>(tileCnt, tile_ptr, tile_cursor, row_ptr);
    int nBuckBlocks = (NNZ + EPB - 1) / EPB;   // 586
    edge_bucket<<<nBuckBlocks, BKT_BLK, 0, stream>>>(rows, cols, vals, tile_cursor, ebuf1);
    row_sort<<<NTILES, RS_BLK, 0, stream>>>(ebuf1, tile_ptr, row_ptr, ebuf2);

    // ---- init (cur16 overwrites ebuf1, which is now dead) ----
    lgcn_init_h<<<g_init, BLK, 0, stream>>>((const float4*)user_emb, (const float4*)item_emb,
                                            (uint2*)cur16, (float4*)out);

    // ---- 3 layers of CSR gather SpMM (fp16 operand, f32 acc) ----
    const int WAVES_PER_BLK = BLK / 64;
    dim3 g_spmm((N_NODES + WAVES_PER_BLK - 1) / WAVES_PER_BLK);
    __half* xa = cur16; __half* xb = nxt16;
    for (int l = 0; l < N_LAYERS; ++l) {
        float scale = (l == N_LAYERS - 1) ? (1.0f / (N_LAYERS + 1)) : 1.0f;
        int writeY = (l < N_LAYERS - 1) ? 1 : 0;
        lgcn_spmm_csr_h4<<<g_spmm, BLK, 0, stream>>>(row_ptr, ebuf2,
                                                     (const uint2*)xa, (uint2*)xb,
                                                     (float4*)out, scale, writeY);
        __half* t = xa; xa = xb; xb = t;
    }
}

// Round 7
// 410.248 us; speedup vs baseline: 14.8976x; 1.1001x over previous
//
#include <hip/hip_runtime.h>
#include <hip/hip_fp16.h>

#define NUM_USERS 100000
#define NUM_ITEMS 50000
#define N_NODES   150000
#define EMB_DIM   64
#define NNZ       4800000
#define N_LAYERS  3

#define TILE_ROWS 256
#define TILE_SHIFT 8
#define NTILES    ((N_NODES + TILE_ROWS - 1) / TILE_ROWS)   // 586
#define COL_BITS  18
#define COL_MASK  ((1 << COL_BITS) - 1)
#define VAL_BITS  14
#define VAL_MASK  ((1 << VAL_BITS) - 1)

static constexpr size_t TOTAL = (size_t)N_NODES * EMB_DIM;   // 9,600,000 floats

// ---------------- init: cur16 = fp16(concat) ----------------
__global__ void lgcn_init_h(const float4* __restrict__ user_emb,
                            const float4* __restrict__ item_emb,
                            uint2* __restrict__ cur16) {
    size_t i = (size_t)blockIdx.x * blockDim.x + threadIdx.x;
    const size_t n4 = TOTAL / 4;
    if (i >= n4) return;
    const size_t ub4 = (size_t)NUM_USERS * EMB_DIM / 4;
    float4 v = (i < ub4) ? user_emb[i] : item_emb[i - ub4];
    __half2 h0 = __floats2half2_rn(v.x, v.y);
    __half2 h1 = __floats2half2_rn(v.z, v.w);
    uint2 u;
    u.x = *reinterpret_cast<unsigned int*>(&h0);
    u.y = *reinterpret_cast<unsigned int*>(&h1);
    cur16[i] = u;
}

// ---------------- tile histogram ----------------
__global__ void tile_hist(const int* __restrict__ rows, int* __restrict__ tileCnt) {
    __shared__ int h[NTILES];
    for (int i = threadIdx.x; i < NTILES; i += blockDim.x) h[i] = 0;
    __syncthreads();
    for (size_t e = (size_t)blockIdx.x * blockDim.x + threadIdx.x; e < NNZ;
         e += (size_t)gridDim.x * blockDim.x)
        atomicAdd(&h[rows[e] >> TILE_SHIFT], 1);
    __syncthreads();
    for (int i = threadIdx.x; i < NTILES; i += blockDim.x) {
        int c = h[i];
        if (c) atomicAdd(&tileCnt[i], c);
    }
}

// ---------------- scan of 586 tile counts (single block) ----------------
__global__ void tile_scan(const int* __restrict__ tileCnt,
                          int* __restrict__ tile_ptr,
                          int* __restrict__ tile_cursor,
                          int* __restrict__ row_ptr) {
    __shared__ int s[1024];
    int t = threadIdx.x;
    int v = (t < NTILES) ? tileCnt[t] : 0;
    s[t] = v;
    __syncthreads();
    for (int off = 1; off < 1024; off <<= 1) {
        int add = (t >= off) ? s[t - off] : 0;
        __syncthreads();
        s[t] += add;
        __syncthreads();
    }
    if (t < NTILES) {
        int ex = s[t] - v;
        tile_ptr[t] = ex;
        tile_cursor[t] = ex;
    }
    if (t == 0) {
        tile_ptr[NTILES] = NNZ;
        row_ptr[N_NODES] = NNZ;
    }
}

// ---------------- pass 1: LDS-staged bucketing by 256-row tile ----------------
#define BKT_BLK 1024
#define EPB     8192    // edges per block (8 per thread)

__global__ __launch_bounds__(BKT_BLK) void
edge_bucket(const int* __restrict__ rows, const int* __restrict__ cols,
            const float* __restrict__ vals, int* __restrict__ tile_cursor,
            int2* __restrict__ ebuf1) {
    __shared__ int2 stage[EPB];     // 64 KB
    __shared__ int  dstIdx[EPB];    // 32 KB
    __shared__ int  hcur[NTILES];
    __shared__ int  lbase[NTILES];
    __shared__ int  gbase[NTILES];

    int tid = threadIdx.x;
    size_t blockStart = (size_t)blockIdx.x * EPB;

    int r[8]; int c[8]; float v[8];
    for (int i = tid; i < NTILES; i += BKT_BLK) hcur[i] = 0;
    __syncthreads();

    #pragma unroll
    for (int k = 0; k < 8; k++) {
        size_t e = blockStart + (size_t)k * BKT_BLK + tid;
        if (e < NNZ) {
            r[k] = rows[e]; c[k] = cols[e]; v[k] = vals[e];
            atomicAdd(&hcur[r[k] >> TILE_SHIFT], 1);
        } else r[k] = -1;
    }
    __syncthreads();

    int cnt = (tid < NTILES) ? hcur[tid] : 0;
    for (int off = 1; off < 1024; off <<= 1) {
        int add = (tid >= off && tid < NTILES) ? hcur[tid - off] : 0;
        __syncthreads();
        if (tid < NTILES) hcur[tid] += add;
        __syncthreads();
    }
    if (tid < NTILES) {
        int ex = hcur[tid] - cnt;
        lbase[tid] = ex;
        gbase[tid] = cnt ? atomicAdd(&tile_cursor[tid], cnt) : 0;
    }
    __syncthreads();
    if (tid < NTILES) hcur[tid] = lbase[tid];
    __syncthreads();

    #pragma unroll
    for (int k = 0; k < 8; k++) {
        if (r[k] >= 0) {
            int t = r[k] >> TILE_SHIFT;
            int slot = atomicAdd(&hcur[t], 1);
            stage[slot] = make_int2(((r[k] & (TILE_ROWS - 1)) << COL_BITS) | c[k],
                                    __float_as_int(v[k]));
            dstIdx[slot] = gbase[t] + (slot - lbase[t]);
        }
    }
    __syncthreads();

    int total = (int)min((size_t)EPB, (size_t)NNZ - blockStart);
    for (int i = tid; i < total; i += BKT_BLK)
        ebuf1[dstIdx[i]] = stage[i];   // coalesced within per-tile runs
}

// ---------------- pass 2: within-tile sort by row; emits row_ptr + packed 4B edges ----------------
#define RS_BLK 512

__global__ __launch_bounds__(RS_BLK) void
row_sort(const int2* __restrict__ ebuf1, const int* __restrict__ tile_ptr,
         int* __restrict__ row_ptr, unsigned int* __restrict__ epack) {
    __shared__ int hist[TILE_ROWS];
    __shared__ int cur256[TILE_ROWS];
    int tid = threadIdx.x;
    int tile = blockIdx.x;
    int s  = tile_ptr[tile];
    int e1 = tile_ptr[tile + 1];

    if (tid < TILE_ROWS) hist[tid] = 0;
    __syncthreads();

    for (int i = s + tid; i < e1; i += RS_BLK)
        atomicAdd(&hist[(unsigned)ebuf1[i].x >> COL_BITS], 1);
    __syncthreads();

    int v = (tid < TILE_ROWS) ? hist[tid] : 0;
    for (int off = 1; off < TILE_ROWS; off <<= 1) {
        int add = (tid >= off && tid < TILE_ROWS) ? hist[tid - off] : 0;
        __syncthreads();
        if (tid < TILE_ROWS) hist[tid] += add;
        __syncthreads();
    }
    if (tid < TILE_ROWS) {
        int excl = hist[tid] - v;
        int rowG = tile * TILE_ROWS + tid;
        if (rowG < N_NODES) row_ptr[rowG] = s + excl;
        cur256[tid] = s + excl;
    }
    __syncthreads();

    for (int i = s + tid; i < e1; i += RS_BLK) {
        int2 m = ebuf1[i];
        int r = (unsigned)m.x >> COL_BITS;
        int pos = atomicAdd(&cur256[r], 1);
        unsigned int col = (unsigned)m.x & COL_MASK;
        float val = __int_as_float(m.y);
        int q = (int)(val * 16384.0f + 0.5f);
        if (q > VAL_MASK) q = VAL_MASK;
        epack[pos] = (col << VAL_BITS) | (unsigned)q;   // scatter within 32KB window (L2)
    }
}

// ---------------- gather SpMM: 8 edge-substreams x 8 lanes, uint4 (8xfp16) loads ----------------
__device__ __forceinline__ void fma8(uint4 xv, float v, float* a) {
    const __half2* h = reinterpret_cast<const __half2*>(&xv);
    #pragma unroll
    for (int k = 0; k < 4; k++) {
        float2 f = __half22float2(h[k]);
        a[2*k]   = fmaf(v, f.x, a[2*k]);
        a[2*k+1] = fmaf(v, f.y, a[2*k+1]);
    }
}

template <int FINAL>
__global__ void lgcn_spmm_csr_h8(const int* __restrict__ row_ptr,
                                 const unsigned int* __restrict__ edges,
                                 const uint4* __restrict__ x16v,
                                 uint4* __restrict__ y16v,
                                 const float4* __restrict__ user_emb,
                                 const float4* __restrict__ item_emb,
                                 const uint4* __restrict__ y1v,
                                 const uint4* __restrict__ y2v,
                                 float4* __restrict__ outv) {
    int wid = blockIdx.x * (blockDim.x >> 6) + (threadIdx.x >> 6);
    if (wid >= N_NODES) return;
    int lane = threadIdx.x & 63;
    int g = lane >> 3;       // edge substream 0..7
    int t = lane & 7;        // dim group: dims 8t..8t+7
    int e  = row_ptr[wid];
    int e1 = row_ptr[wid + 1];
    float a[8] = {0.f,0.f,0.f,0.f,0.f,0.f,0.f,0.f};
    const float inv = 1.0f / 16384.0f;

    for (; e + 8 <= e1; e += 8) {
        unsigned int m = edges[e + g];
        uint4 xv = x16v[(size_t)(m >> VAL_BITS) * 8 + t];
        fma8(xv, (float)(m & VAL_MASK) * inv, a);
    }
    int rem = e1 - e;        // 0..7
    if (g < rem) {
        unsigned int m = edges[e + g];
        uint4 xv = x16v[(size_t)(m >> VAL_BITS) * 8 + t];
        fma8(xv, (float)(m & VAL_MASK) * inv, a);
    }

    // fold the 8 substreams (xor 8,16,32 flips g bits)
    #pragma unroll
    for (int k = 0; k < 8; k++) a[k] += __shfl_xor(a[k], 8);
    #pragma unroll
    for (int k = 0; k < 8; k++) a[k] += __shfl_xor(a[k], 16);
    #pragma unroll
    for (int k = 0; k < 8; k++) a[k] += __shfl_xor(a[k], 32);

    if (lane < 8) {
        if (!FINAL) {
            __half2 h[4];
            #pragma unroll
            for (int k = 0; k < 4; k++) h[k] = __floats2half2_rn(a[2*k], a[2*k+1]);
            uint4 u = *reinterpret_cast<uint4*>(h);
            y16v[(size_t)wid * 8 + t] = u;
        } else {
            // fused: out = (in + y1 + y2 + a) * 0.25, dims 8t..8t+7
            const float4* inp = (wid < NUM_USERS)
                ? (user_emb + (size_t)wid * 16)
                : (item_emb + (size_t)(wid - NUM_USERS) * 16);
            uint4 u1 = y1v[(size_t)wid * 8 + t];
            uint4 u2 = y2v[(size_t)wid * 8 + t];
            const __half2* h1 = reinterpret_cast<const __half2*>(&u1);
            const __half2* h2 = reinterpret_cast<const __half2*>(&u2);
            float4 o0 = inp[2*t];
            float4 o1 = inp[2*t + 1];
            float s[8];
            #pragma unroll
            for (int k = 0; k < 4; k++) {
                float2 f1 = __half22float2(h1[k]);
                float2 f2 = __half22float2(h2[k]);
                s[2*k]   = f1.x + f2.x;
                s[2*k+1] = f1.y + f2.y;
            }
            o0.x = (o0.x + s[0] + a[0]) * 0.25f;
            o0.y = (o0.y + s[1] + a[1]) * 0.25f;
            o0.z = (o0.z + s[2] + a[2]) * 0.25f;
            o0.w = (o0.w + s[3] + a[3]) * 0.25f;
            o1.x = (o1.x + s[4] + a[4]) * 0.25f;
            o1.y = (o1.y + s[5] + a[5]) * 0.25f;
            o1.z = (o1.z + s[6] + a[6]) * 0.25f;
            o1.w = (o1.w + s[7] + a[7]) * 0.25f;
            outv[(size_t)wid * 16 + 2*t]     = o0;
            outv[(size_t)wid * 16 + 2*t + 1] = o1;
        }
    }
}

// ---------------- fallback (round-1 atomic path), used if ws too small ----------------
__global__ void lgcn_init_f(const float4* __restrict__ user_emb,
                            const float4* __restrict__ item_emb,
                            float4* __restrict__ cur,
                            float4* __restrict__ acc) {
    size_t i = (size_t)blockIdx.x * blockDim.x + threadIdx.x;
    const size_t n4 = TOTAL / 4;
    if (i >= n4) return;
    const size_t ub4 = (size_t)NUM_USERS * EMB_DIM / 4;
    float4 v = (i < ub4) ? user_emb[i] : item_emb[i - ub4];
    cur[i] = v;
    acc[i] = v;
}

__global__ void lgcn_spmm_scatter(const int* __restrict__ rows,
                                  const int* __restrict__ cols,
                                  const float* __restrict__ vals,
                                  const float* __restrict__ x,
                                  float* __restrict__ y) {
    size_t t = (size_t)blockIdx.x * blockDim.x + threadIdx.x;
    if (t >= (size_t)NNZ * EMB_DIM) return;
    int e = (int)(t >> 6);
    int d = (int)(t & 63);
    atomicAdd(&y[(size_t)rows[e] * EMB_DIM + d], vals[e] * x[(size_t)cols[e] * EMB_DIM + d]);
}

__global__ void lgcn_accum(float4* __restrict__ acc, const float4* __restrict__ nxt, float scale) {
    size_t i = (size_t)blockIdx.x * blockDim.x + threadIdx.x;
    const size_t n4 = TOTAL / 4;
    if (i >= n4) return;
    float4 a = acc[i]; float4 b = nxt[i];
    a.x = (a.x + b.x) * scale; a.y = (a.y + b.y) * scale;
    a.z = (a.z + b.z) * scale; a.w = (a.w + b.w) * scale;
    acc[i] = a;
}

extern "C" void kernel_launch(void* const* d_in, const int* in_sizes, int n_in,
                              void* d_out, int out_size, void* d_ws, size_t ws_size,
                              hipStream_t stream) {
    const float* user_emb = (const float*)d_in[0];
    const float* item_emb = (const float*)d_in[1];
    const int*   rows     = (const int*)d_in[2];
    const int*   cols     = (const int*)d_in[3];
    const float* vals     = (const float*)d_in[4];
    float* out = (float*)d_out;

    const int BLK = 256;
    const size_t n4 = TOTAL / 4;
    dim3 g_init((n4 + BLK - 1) / BLK);

    // workspace layout — y1/y2 ALIAS ebuf1 (dead after row_sort)
    char* p = (char*)d_ws;
    unsigned int* epack = (unsigned int*)p;  p += (size_t)NNZ * sizeof(unsigned int); // 19.2 MB
    __half* y1 = (__half*)p;                                                           // 19.2 MB (aliases ebuf1 lo)
    int2*   ebuf1 = (int2*)p;                p += (size_t)NNZ * sizeof(int2);          // 38.4 MB
    __half* y2 = y1 + TOTAL;                                                           // 19.2 MB (aliases ebuf1 hi)
    __half* cur16 = (__half*)p;              p += TOTAL * sizeof(__half);              // 19.2 MB
    __half* y3 = (__half*)p;                 p += TOTAL * sizeof(__half);              // 19.2 MB
    int*    tileCnt = (int*)p;               p += (size_t)NTILES * sizeof(int);
    int*    tile_ptr = (int*)p;              p += (size_t)(NTILES + 1) * sizeof(int);
    int*    tile_cursor = (int*)p;           p += (size_t)NTILES * sizeof(int);
    int*    row_ptr = (int*)p;               p += (size_t)(N_NODES + 1) * sizeof(int);
    size_t needed = (size_t)(p - (char*)d_ws);

    if (ws_size < needed) {
        float* fcur = (float*)d_ws;
        float* fnxt = fcur + TOTAL;
        lgcn_init_f<<<g_init, BLK, 0, stream>>>((const float4*)user_emb, (const float4*)item_emb,
                                                (float4*)fcur, (float4*)out);
        const size_t st = (size_t)NNZ * EMB_DIM;
        dim3 g_scat((st + BLK - 1) / BLK);
        for (int l = 0; l < N_LAYERS; ++l) {
            hipMemsetAsync(fnxt, 0, TOTAL * sizeof(float), stream);
            lgcn_spmm_scatter<<<g_scat, BLK, 0, stream>>>(rows, cols, vals, fcur, fnxt);
            float scale = (l == N_LAYERS - 1) ? (1.0f / (N_LAYERS + 1)) : 1.0f;
            lgcn_accum<<<g_init, BLK, 0, stream>>>((float4*)out, (const float4*)fnxt, scale);
            float* t = fcur; fcur = fnxt; fnxt = t;
        }
        return;
    }

    // ---- two-pass row sort (once per call) ----
    hipMemsetAsync(tileCnt, 0, (size_t)NTILES * sizeof(int), stream);
    tile_hist<<<1024, 256, 0, stream>>>(rows, tileCnt);
    tile_scan<<<1, 1024, 0, stream>>>(tileCnt, tile_ptr, tile_cursor, row_ptr);
    int nBuckBlocks = (NNZ + EPB - 1) / EPB;   // 586
    edge_bucket<<<nBuckBlocks, BKT_BLK, 0, stream>>>(rows, cols, vals, tile_cursor, ebuf1);
    row_sort<<<NTILES, RS_BLK, 0, stream>>>(ebuf1, tile_ptr, row_ptr, epack);

    // ---- init fp16 x0 (cur16 does NOT alias ebuf1; y1/y2 do, and are written after row_sort) ----
    lgcn_init_h<<<g_init, BLK, 0, stream>>>((const float4*)user_emb, (const float4*)item_emb,
                                            (uint2*)cur16);

    // ---- 3 layers; final layer fuses the combine ----
    const int WAVES_PER_BLK = BLK / 64;
    dim3 g_spmm((N_NODES + WAVES_PER_BLK - 1) / WAVES_PER_BLK);
    lgcn_spmm_csr_h8<0><<<g_spmm, BLK, 0, stream>>>(row_ptr, epack,
        (const uint4*)cur16, (uint4*)y1, nullptr, nullptr, nullptr, nullptr, nullptr);
    lgcn_spmm_csr_h8<0><<<g_spmm, BLK, 0, stream>>>(row_ptr, epack,
        (const uint4*)y1, (uint4*)y2, nullptr, nullptr, nullptr, nullptr, nullptr);
    lgcn_spmm_csr_h8<1><<<g_spmm, BLK, 0, stream>>>(row_ptr, epack,
        (const uint4*)y2, (uint4*)y3,
        (const float4*)user_emb, (const float4*)item_emb,
        (const uint4*)y1, (const uint4*)y2, (float4*)out);
}